// Round 2
// baseline (914.469 us; speedup 1.0000x reference)
//
#include <hip/hip_runtime.h>
#include <cstddef>

// Problem constants (from reference)
#define NB     64    // batch
#define NHQ    32    // q heads
#define NHKV   8     // kv heads
#define HD     128   // head dim
#define BS     16    // kv block size (S)
#define NMB    128   // max kv blocks per seq
#define NG     4     // q heads per kv head
#define CHUNK  512   // split-K chunk (positions)
#define NCHUNK 4     // LMAX / CHUNK = 2048/512
#define QK_SCALE 0.08838834764831845f
#define WS_STRIDE 520  // floats per (bh,chunk) partial: 4 m + 4 l + 512 o

// ---------------- Kernel 1: per-chunk partial attention ----------------
__global__ __launch_bounds__(256, 4)
void pa_partial(const float* __restrict__ q,
                const float* __restrict__ k_cache,
                const float* __restrict__ v_cache,
                const int*   __restrict__ block_tables,
                const int*   __restrict__ context_lens,
                float*       __restrict__ ws)
{
    const int c   = blockIdx.x & (NCHUNK - 1);
    const int bh  = blockIdx.x >> 2;
    const int b   = bh >> 3;
    const int h   = bh & 7;
    const int len = context_lens[b];
    const int start = c * CHUNK;
    if (start >= len) return;                  // uniform per workgroup
    const int n = min(len - start, CHUNK);

    const int tid  = threadIdx.x;
    const int team = tid >> 5;                 // 0..7
    const int lane = tid & 31;                 // dims [lane*4, lane*4+4)

    __shared__ float smem[8 * NG * HD];        // 16 KB union: s_p (CHUNK*4) then s_acc[8][4][128]
    __shared__ int   s_bt[CHUNK / BS];         // 32 block-table entries for this chunk
    __shared__ float s_m[NG], s_l[NG];

    float* s_p = smem;

    if (tid < CHUNK / BS) s_bt[tid] = block_tables[b * NMB + (start >> 4) + tid];

    // q fragments (pre-scaled)
    const float* qb = q + ((size_t)b * NHQ + (size_t)h * NG) * HD + lane * 4;
    float4 q0 = *(const float4*)(qb);
    float4 q1 = *(const float4*)(qb + HD);
    float4 q2 = *(const float4*)(qb + 2 * HD);
    float4 q3 = *(const float4*)(qb + 3 * HD);
    q0.x *= QK_SCALE; q0.y *= QK_SCALE; q0.z *= QK_SCALE; q0.w *= QK_SCALE;
    q1.x *= QK_SCALE; q1.y *= QK_SCALE; q1.z *= QK_SCALE; q1.w *= QK_SCALE;
    q2.x *= QK_SCALE; q2.y *= QK_SCALE; q2.z *= QK_SCALE; q2.w *= QK_SCALE;
    q3.x *= QK_SCALE; q3.y *= QK_SCALE; q3.z *= QK_SCALE; q3.w *= QK_SCALE;

    __syncthreads();  // s_bt ready

    const float* kbase = k_cache + (size_t)h * HD + lane * 4;
    const float* vbase = v_cache + (size_t)h * HD + lane * 4;

    auto soff = [&](int p) -> size_t {  // p is chunk-local
        return ((size_t)s_bt[p >> 4] * BS + (size_t)(p & 15)) * (NHKV * HD);
    };

    const bool l1 = (lane & 1) != 0;
    const bool l2 = (lane & 2) != 0;

    // ---------------- Phase 1: scores ----------------
    // multi-value butterfly: 5 shuffles reduce all 4 head-dots; lanes 0..3 hold heads 0..3
    auto qk_one = [&](int p, float4 k4) {
        float d0 = q0.x * k4.x + q0.y * k4.y + q0.z * k4.z + q0.w * k4.w;
        float d1 = q1.x * k4.x + q1.y * k4.y + q1.z * k4.z + q1.w * k4.w;
        float d2 = q2.x * k4.x + q2.y * k4.y + q2.z * k4.z + q2.w * k4.w;
        float d3 = q3.x * k4.x + q3.y * k4.y + q3.z * k4.z + q3.w * k4.w;
        float u  = l1 ? d1 : d0, uw = l1 ? d0 : d1;
        u += __shfl_xor(uw, 1, 32);
        float v  = l1 ? d3 : d2, vw = l1 ? d2 : d3;
        v += __shfl_xor(vw, 1, 32);
        float x  = l2 ? v : u,  y  = l2 ? u : v;
        x += __shfl_xor(y, 2, 32);
        x += __shfl_xor(x, 4, 32);
        x += __shfl_xor(x, 8, 32);
        x += __shfl_xor(x, 16, 32);
        if (lane < 4) s_p[4 * p + lane] = x;   // lane == head index
    };

    {
        int p = team;
        for (; p + 56 < n; p += 64) {
            float4 kk[8];
#pragma unroll
            for (int u = 0; u < 8; ++u) kk[u] = *(const float4*)(kbase + soff(p + 8 * u));
#pragma unroll
            for (int u = 0; u < 8; ++u) qk_one(p + 8 * u, kk[u]);
        }
        for (; p < n; p += 8) {
            qk_one(p, *(const float4*)(kbase + soff(p)));
        }
    }
    __syncthreads();

    // ---------------- Phase 2: chunk-local softmax (one wave per head) ----------------
    {
        const int wv = tid >> 6;   // head within group
        const int wl = tid & 63;
        float m = -INFINITY;
        for (int p = wl; p < n; p += 64) m = fmaxf(m, s_p[4 * p + wv]);
#pragma unroll
        for (int off = 32; off >= 1; off >>= 1) m = fmaxf(m, __shfl_xor(m, off, 64));
        float l = 0.0f;
        for (int p = wl; p < n; p += 64) {
            float e = __expf(s_p[4 * p + wv] - m);
            s_p[4 * p + wv] = e;
            l += e;
        }
#pragma unroll
        for (int off = 32; off >= 1; off >>= 1) l += __shfl_xor(l, off, 64);
        if (wl == 0) { s_m[wv] = m; s_l[wv] = l; }
    }
    __syncthreads();

    // ---------------- Phase 3: unnormalized O = P . V ----------------
    float4 a0 = make_float4(0.f, 0.f, 0.f, 0.f);
    float4 a1 = a0, a2 = a0, a3 = a0;

    auto pv_one = [&](int p, float4 v4) {
        const float* sp = s_p + 4 * p;
        float w0 = sp[0], w1 = sp[1], w2 = sp[2], w3 = sp[3];
        a0.x += w0 * v4.x; a0.y += w0 * v4.y; a0.z += w0 * v4.z; a0.w += w0 * v4.w;
        a1.x += w1 * v4.x; a1.y += w1 * v4.y; a1.z += w1 * v4.z; a1.w += w1 * v4.w;
        a2.x += w2 * v4.x; a2.y += w2 * v4.y; a2.z += w2 * v4.z; a2.w += w2 * v4.w;
        a3.x += w3 * v4.x; a3.y += w3 * v4.y; a3.z += w3 * v4.z; a3.w += w3 * v4.w;
    };

    {
        int p = team;
        for (; p + 56 < n; p += 64) {
            float4 vv[8];
#pragma unroll
            for (int u = 0; u < 8; ++u) vv[u] = *(const float4*)(vbase + soff(p + 8 * u));
#pragma unroll
            for (int u = 0; u < 8; ++u) pv_one(p + 8 * u, vv[u]);
        }
        for (; p < n; p += 8) {
            pv_one(p, *(const float4*)(vbase + soff(p)));
        }
    }
    __syncthreads();   // everyone done READING s_p before we overwrite with s_acc

    float (*s_acc)[NG][HD] = (float (*)[NG][HD])smem;
    *(float4*)&s_acc[team][0][lane * 4] = a0;
    *(float4*)&s_acc[team][1][lane * 4] = a1;
    *(float4*)&s_acc[team][2][lane * 4] = a2;
    *(float4*)&s_acc[team][3][lane * 4] = a3;
    __syncthreads();

    float* wsb = ws + (size_t)(bh * NCHUNK + c) * WS_STRIDE;
    if (tid < 128) {
        const int j  = tid >> 5;          // head within group
        const int d4 = (tid & 31) << 2;   // dim chunk
        float sx = 0.f, sy = 0.f, sz = 0.f, sw = 0.f;
#pragma unroll
        for (int t = 0; t < 8; ++t) {
            const float* a = &s_acc[t][j][d4];
            sx += a[0]; sy += a[1]; sz += a[2]; sw += a[3];
        }
        *(float4*)(wsb + 8 + j * HD + d4) = make_float4(sx, sy, sz, sw);  // unnormalized
    }
    if (tid < NG) { wsb[tid] = s_m[tid]; wsb[NG + tid] = s_l[tid]; }
}

// ---------------- Kernel 2: merge chunk partials ----------------
__global__ __launch_bounds__(256)
void pa_reduce(const int* __restrict__ context_lens,
               const float* __restrict__ ws,
               float* __restrict__ out)
{
    const int bh  = blockIdx.x;     // 0..511
    const int b   = bh >> 3;
    const int h   = bh & 7;
    const int len = context_lens[b];
    const int nc  = (len + CHUNK - 1) / CHUNK;   // active chunks, >= 1
    const float* base = ws + (size_t)bh * NCHUNK * WS_STRIDE;

    for (int e = threadIdx.x; e < NG * HD; e += 256) {   // e = j*128 + d
        const int j = e >> 7;
        float m = -INFINITY;
        for (int cI = 0; cI < nc; ++cI) m = fmaxf(m, base[cI * WS_STRIDE + j]);
        float acc = 0.f, l = 0.f;
        for (int cI = 0; cI < nc; ++cI) {
            const float w = __expf(base[cI * WS_STRIDE + j] - m);
            l   += w * base[cI * WS_STRIDE + NG + j];
            acc += w * base[cI * WS_STRIDE + 8 + e];
        }
        out[((size_t)b * NHQ + (size_t)h * NG) * HD + e] = acc / l;
    }
}

extern "C" void kernel_launch(void* const* d_in, const int* in_sizes, int n_in,
                              void* d_out, int out_size, void* d_ws, size_t ws_size,
                              hipStream_t stream) {
    const float* q            = (const float*)d_in[0];
    const float* k_cache      = (const float*)d_in[1];
    const float* v_cache      = (const float*)d_in[2];
    const int*   block_tables = (const int*)d_in[3];
    const int*   context_lens = (const int*)d_in[4];
    float*       out          = (float*)d_out;
    float*       ws           = (float*)d_ws;

    pa_partial<<<dim3(NB * NHKV * NCHUNK), dim3(256), 0, stream>>>(
        q, k_cache, v_cache, block_tables, context_lens, ws);
    pa_reduce<<<dim3(NB * NHKV), dim3(256), 0, stream>>>(
        context_lens, ws, out);
}